// Round 2
// baseline (836.102 us; speedup 1.0000x reference)
//
#include <hip/hip_runtime.h>
#include <hip/hip_bf16.h>
#include <math.h>

// Problem constants (fixed by the reference: B=4,S=2048,H=1024,D=4096)
#define H_DIM 1024
#define NBASIS 8
#define K_DIM 9216                // 8*H (spline, k=h*8+j) + H (silu, k=8192+h)
#define K_SILU 8192
#define BM 256                    // block tile (M and O)
#define BK 64                     // K tile (bf16 elements)
#define NKT (K_DIM / BK)          // 144 (even)

typedef __bf16 bf16x8 __attribute__((ext_vector_type(8)));
typedef float f32x4 __attribute__((ext_vector_type(4)));
typedef float f32x16 __attribute__((ext_vector_type(16)));
typedef unsigned short u16x8 __attribute__((ext_vector_type(8)));

__device__ __forceinline__ unsigned short f2bf(float f) {
    __hip_bfloat16 h = __float2bfloat16(f);   // RNE
    return __builtin_bit_cast(unsigned short, h);
}

// ---------------------------------------------------------------------------
// Kernel 1: A[n][h*8+j] = bf16 bases, A[n][8192+h] = bf16 silu(x)
// ---------------------------------------------------------------------------
__global__ void prep_a_kernel(const float* __restrict__ x,
                              unsigned short* __restrict__ A, int total) {
    int idx = blockIdx.x * 256 + threadIdx.x;   // idx = n*H + h
    if (idx >= total) return;
    int n = idx >> 10;
    int h = idx & (H_DIM - 1);
    float v = x[idx];

    float sil = v / (1.0f + __expf(-v));

    float b[11];
#pragma unroll
    for (int i = 0; i < 11; ++i) {
        const float gi  = (float)(i - 3) * 0.4f + (-1.0f);
        const float gi1 = (float)(i - 2) * 0.4f + (-1.0f);
        b[i] = (v >= gi && v < gi1) ? 1.0f : 0.0f;
    }
#pragma unroll
    for (int k = 1; k <= 3; ++k) {
#pragma unroll
        for (int i = 0; i + k < 11; ++i) {
            const float gi   = (float)(i - 3) * 0.4f + (-1.0f);
            const float gi1  = (float)(i - 2) * 0.4f + (-1.0f);
            const float gik  = (float)(i + k - 3) * 0.4f + (-1.0f);
            const float gik1 = (float)(i + k - 2) * 0.4f + (-1.0f);
            float left  = (v - gi)   * (1.0f / (gik - gi));
            float right = (gik1 - v) * (1.0f / (gik1 - gi1));
            b[i] = left * b[i] + right * b[i + 1];
        }
    }

    u16x8 pack;
#pragma unroll
    for (int j = 0; j < NBASIS; ++j) pack[j] = f2bf(b[j]);

    size_t rowBase = (size_t)n * K_DIM;
    *reinterpret_cast<u16x8*>(A + rowBase + (size_t)h * 8) = pack;
    A[rowBase + K_SILU + h] = f2bf(sil);
}

// ---------------------------------------------------------------------------
// Kernel 2: B[o][h*8+j] = bf16(sw*scaler), B[o][8192+h] = bf16(bw)
// ---------------------------------------------------------------------------
__global__ void prep_b_kernel(const float* __restrict__ bw,
                              const float* __restrict__ sw,
                              const float* __restrict__ ss,
                              unsigned short* __restrict__ Bm, int total) {
    int idx = blockIdx.x * 256 + threadIdx.x;   // idx = o*H + h
    if (idx >= total) return;

    const float4* p = (const float4*)(sw + (size_t)idx * 8);
    float4 w0 = p[0], w1 = p[1];
    float sc = ss[idx];

    u16x8 pack;
    pack[0] = f2bf(w0.x * sc); pack[1] = f2bf(w0.y * sc);
    pack[2] = f2bf(w0.z * sc); pack[3] = f2bf(w0.w * sc);
    pack[4] = f2bf(w1.x * sc); pack[5] = f2bf(w1.y * sc);
    pack[6] = f2bf(w1.z * sc); pack[7] = f2bf(w1.w * sc);

    int o = idx >> 10;
    int h = idx & (H_DIM - 1);
    size_t rowBase = (size_t)o * K_DIM;
    *reinterpret_cast<u16x8*>(Bm + rowBase + (size_t)h * 8) = pack;
    Bm[rowBase + K_SILU + h] = f2bf(bw[idx]);
}

// ---------------------------------------------------------------------------
// Kernel 3: C = gelu(A @ B^T) — 256x256 tile, 8-wave, 8-phase counted-vmcnt
// schedule (T3+T4), chunk-XOR conflict-free LDS (T2), setprio (T5), bijective
// XCD swizzle (T1). This round: 32x32x16 MFMA (matrix pipe +15% vs 16x16x32;
// m119: 2495 vs 2176 TF) + lgkmcnt(8) drain hint on 12-read phases.
//   A-frag layout (family pattern, cf. verified 16x16: row=l&15,k=(l>>4)*8+j):
//     row = l&31, k = (l>>5)*8 + j.  C/D (HW-verified m74/m101):
//     col = l&31, row = (reg&3) + 8*(reg>>2) + 4*(l>>5).
// ---------------------------------------------------------------------------
#define BARRIER()    do { __builtin_amdgcn_s_barrier(); \
                          __builtin_amdgcn_sched_barrier(0); } while (0)
#define WAIT_LGKM0() do { asm volatile("s_waitcnt lgkmcnt(0)" ::: "memory"); \
                          __builtin_amdgcn_sched_barrier(0); } while (0)
#define WAIT_VM6()   do { asm volatile("s_waitcnt vmcnt(6)" ::: "memory"); \
                          __builtin_amdgcn_sched_barrier(0); } while (0)
#define HINT_LGKM8() asm volatile("s_waitcnt lgkmcnt(8)" ::: "memory")

// Chunk-XOR swizzle: logical chunk c at row r lives in slot c ^ (r&7).
// A half-tile read: 8 frags (mi2 x ks) for this wave's quadrant.
__device__ __forceinline__ void load_a32(const unsigned short* hp, int wr,
                                         int l31, int hi, bf16x8* f) {
#pragma unroll
    for (int ks = 0; ks < 4; ++ks)
#pragma unroll
        for (int mi2 = 0; mi2 < 2; ++mi2) {
            const int row = wr * 64 + mi2 * 32 + l31;   // row&7 == l31&7
            const int c   = ks * 2 + hi;
            f[mi2 * 4 + ks] = *reinterpret_cast<const bf16x8*>(
                &hp[row * 64 + ((c ^ (l31 & 7)) << 3)]);
        }
}
// B half-tile read: 4 frags (ks) for this wave's n-column group.
__device__ __forceinline__ void load_b32(const unsigned short* hp, int wc,
                                         int l31, int hi, bf16x8* f) {
#pragma unroll
    for (int ks = 0; ks < 4; ++ks) {
        const int row = wc * 32 + l31;
        const int c   = ks * 2 + hi;
        f[ks] = *reinterpret_cast<const bf16x8*>(
            &hp[row * 64 + ((c ^ (l31 & 7)) << 3)]);
    }
}

template<int QA, int QB>
__device__ __forceinline__ void mfma_quad(const bf16x8* aF, const bf16x8* bF,
                                          f32x16 (&acc)[4][2]) {
    __builtin_amdgcn_s_setprio(1);
#pragma unroll
    for (int ks = 0; ks < 4; ++ks)
#pragma unroll
        for (int mi2 = 0; mi2 < 2; ++mi2)
            acc[QA * 2 + mi2][QB] = __builtin_amdgcn_mfma_f32_32x32x16_bf16(
                aF[mi2 * 4 + ks], bF[ks], acc[QA * 2 + mi2][QB], 0, 0, 0);
    __builtin_amdgcn_s_setprio(0);
}

__global__ __launch_bounds__(512, 2) void gemm_kan(
    const unsigned short* __restrict__ A,
    const unsigned short* __restrict__ B,
    float* __restrict__ out, int M, int D) {

    // 2 dbuf x {A0,A1,B0,B1} halves of 128x64 bf16 = 128 KiB
    __shared__ __align__(16) unsigned short lds[2][4][128 * 64];

    const int tid  = threadIdx.x;
    const int lane = tid & 63;
    const int w    = tid >> 6;          // wave 0..7
    const int wr   = w >> 2;            // 0..1  (M half)
    const int wc   = w & 3;             // 0..3  (N quarter)
    const int l31  = lane & 31, hi = lane >> 5;

    // T1: bijective XCD swizzle (nwg = 512, 512 % 8 == 0)
    const int nwg = gridDim.x;
    const int cpx = nwg >> 3;
    int bid = blockIdx.x;
    bid = (bid & 7) * cpx + (bid >> 3);
    const int nOB  = D / BM;            // 16
    const int mBlk = bid / nOB;
    const int oBlk = bid % nOB;

    // ---- staging geometry (unchanged, verified r1) ------------------------
    // Half-tile = 128 rows x 64 bf16 (16 KiB); wave w stages rows
    // [w*16, w*16+16) as 2 x global_load_lds (1024 B each, linear dest).
    // Source pre-swizzled: global chunk (lane&7)^(lane>>3) -> slot lane&7.
    // A-half q = rows {wr*128 + q*64 + [0,64)}; B-half q = {wc*64 + q*32 + [0,32)}.
    const int sub = lane >> 3;
    const int cg  = ((lane & 7) ^ sub) * 8;
    const unsigned short *sA[2][2], *sB[2][2];
#pragma unroll
    for (int h = 0; h < 2; ++h)
#pragma unroll
        for (int l = 0; l < 2; ++l) {
            const int r  = w * 16 + l * 8 + sub;          // 0..127
            const int gA = mBlk * BM + (r >> 6) * 128 + h * 64 + (r & 63);
            const int gB = oBlk * BM + (r >> 5) * 64  + h * 32 + (r & 31);
            sA[h][l] = A + (size_t)gA * K_DIM + cg;
            sB[h][l] = B + (size_t)gB * K_DIM + cg;
        }
    const int ldsOff = w * 1024;        // elements; +l*512 per load

    auto stageA = [&](int db, int h, int kt) {
#pragma unroll
        for (int l = 0; l < 2; ++l)
            __builtin_amdgcn_global_load_lds(
                (const __attribute__((address_space(1))) void*)(sA[h][l] + (size_t)kt * BK),
                (__attribute__((address_space(3))) void*)(&lds[db][h][ldsOff + l * 512]),
                16, 0, 0);
    };
    auto stageB = [&](int db, int h, int kt) {
#pragma unroll
        for (int l = 0; l < 2; ++l)
            __builtin_amdgcn_global_load_lds(
                (const __attribute__((address_space(1))) void*)(sB[h][l] + (size_t)kt * BK),
                (__attribute__((address_space(3))) void*)(&lds[db][2 + h][ldsOff + l * 512]),
                16, 0, 0);
    };

    f32x16 acc[4][2];
#pragma unroll
    for (int i = 0; i < 4; ++i)
#pragma unroll
        for (int j = 0; j < 2; ++j)
            acc[i][j] = (f32x16)(0.f);
    bf16x8 aF[8], bF[4];

    // ---- prologue: tile0 (all 4 halves, buf0) + tile1 {A0,B1,A1} (buf1) ---
    stageA(0, 0, 0); stageB(0, 1, 0); stageA(0, 1, 0); stageB(0, 0, 0);
    stageA(1, 0, 1); stageB(1, 1, 1); stageA(1, 1, 1);
    WAIT_VM6();                          // tile0 complete; 3 halves in flight
    BARRIER();

    // ---- main loop: 2 K-tiles / iteration, 8 phases -----------------------
    // Quadrant order per K-tile: (QA,QB) = (0,0)(0,1)(1,1)(1,0); A-half = QA,
    // B-half = QB. Stage slots/targets identical to r1 (safety audit holds:
    // each staged half's last ds_read is >= 1 phase-barrier-pair earlier).
    for (int it = 0; it < NKT / 2; ++it) {
        const int t  = it << 1;                          // buf0 tile
        const int t2 = (t + 2 < NKT) ? t + 2 : NKT - 1;  // clamp keeps vmcnt
        const int t3 = (t + 3 < NKT) ? t + 3 : NKT - 1;  // counts uniform

        // ph1: quad(0,0) of t (buf0); stage B0(t+1)->buf1
        load_a32(&lds[0][0][0], wr, l31, hi, aF);
        load_b32(&lds[0][2][0], wc, l31, hi, bF);
        stageB(1, 0, t + 1);
        HINT_LGKM8();
        BARRIER(); WAIT_LGKM0();
        mfma_quad<0, 0>(aF, bF, acc);
        BARRIER();

        // ph2: quad(0,1); stage A0(t+2)->buf0 (A0 last read ph1)
        load_b32(&lds[0][3][0], wc, l31, hi, bF);
        stageA(0, 0, t2);
        BARRIER(); WAIT_LGKM0();
        mfma_quad<0, 1>(aF, bF, acc);
        BARRIER();

        // ph3: quad(1,1); stage B1(t+2)->buf0 (B1 last read ph2)
        load_a32(&lds[0][1][0], wr, l31, hi, aF);
        stageB(0, 1, t2);
        BARRIER(); WAIT_LGKM0();
        mfma_quad<1, 1>(aF, bF, acc);
        BARRIER();

        // ph4: quad(1,0); stage A1(t+2)->buf0 (A1 last read ph3)
        load_b32(&lds[0][2][0], wc, l31, hi, bF);
        stageA(0, 1, t2);
        BARRIER(); WAIT_LGKM0();
        mfma_quad<1, 0>(aF, bF, acc);
        WAIT_VM6();                      // tile t+1 fully staged
        BARRIER();

        // ph5: quad(0,0) of t+1 (buf1); stage B0(t+2)->buf0 (buf0 reads done)
        load_a32(&lds[1][0][0], wr, l31, hi, aF);
        load_b32(&lds[1][2][0], wc, l31, hi, bF);
        stageB(0, 0, t2);
        HINT_LGKM8();
        BARRIER(); WAIT_LGKM0();
        mfma_quad<0, 0>(aF, bF, acc);
        BARRIER();

        // ph6: quad(0,1); stage A0(t+3)->buf1
        load_b32(&lds[1][3][0], wc, l31, hi, bF);
        stageA(1, 0, t3);
        BARRIER(); WAIT_LGKM0();
        mfma_quad<0, 1>(aF, bF, acc);
        BARRIER();

        // ph7: quad(1,1); stage B1(t+3)->buf1
        load_a32(&lds[1][1][0], wr, l31, hi, aF);
        stageB(1, 1, t3);
        BARRIER(); WAIT_LGKM0();
        mfma_quad<1, 1>(aF, bF, acc);
        BARRIER();

        // ph8: quad(1,0); stage A1(t+3)->buf1
        load_b32(&lds[1][2][0], wc, l31, hi, bF);
        stageA(1, 1, t3);
        BARRIER(); WAIT_LGKM0();
        mfma_quad<1, 0>(aF, bF, acc);
        WAIT_VM6();                      // tile t+2 fully staged
        BARRIER();
    }
    asm volatile("s_waitcnt vmcnt(0)" ::: "memory");  // drain tail prefetch

    // ---- epilogue: exact (erf) GELU, fp32 store ---------------------------
    // 32x32 C/D layout (m74/m101): col = l&31, row = (reg&3)+8*(reg>>2)+4*hi
    const int mBase = mBlk * BM + wr * 128;
    const int oBase = oBlk * BM + wc * 64 + l31;
#pragma unroll
    for (int ai = 0; ai < 4; ++ai) {
#pragma unroll
        for (int ni = 0; ni < 2; ++ni) {
            const int o = oBase + ni * 32;
#pragma unroll
            for (int reg = 0; reg < 16; ++reg) {
                const int m = mBase + ai * 32 + (reg & 3) + ((reg >> 2) << 3) + (hi << 2);
                float v = acc[ai][ni][reg];
                float gv = 0.5f * v * (1.0f + erff(v * 0.70710678118654752f));
                out[(size_t)m * D + o] = gv;
            }
        }
    }
}

// ---------------------------------------------------------------------------
extern "C" void kernel_launch(void* const* d_in, const int* in_sizes, int n_in,
                              void* d_out, int out_size, void* d_ws, size_t ws_size,
                              hipStream_t stream) {
    const float* x  = (const float*)d_in[0];   // (B,S,H)
    const float* bw = (const float*)d_in[1];   // (D,H)
    const float* sw = (const float*)d_in[2];   // (D,H,8)
    const float* ss = (const float*)d_in[3];   // (D,H)
    float* out = (float*)d_out;

    const int M = in_sizes[0] / H_DIM;         // 8192
    const int D = in_sizes[1] / H_DIM;         // 4096

    unsigned short* Aws = (unsigned short*)d_ws;              // M x K bf16
    unsigned short* Bws = Aws + (size_t)M * K_DIM;            // D x K bf16

    const int totA = M * H_DIM;
    prep_a_kernel<<<(totA + 255) / 256, 256, 0, stream>>>(x, Aws, totA);
    const int totB = D * H_DIM;
    prep_b_kernel<<<(totB + 255) / 256, 256, 0, stream>>>(bw, sw, ss, Bws, totB);

    dim3 grid((M / BM) * (D / BM));            // 32*16 = 512 blocks
    gemm_kan<<<grid, 512, 0, stream>>>(Aws, Bws, out, M, D);
}

// Round 3
// 750.931 us; speedup vs baseline: 1.1134x; 1.1134x over previous
//
#include <hip/hip_runtime.h>
#include <hip/hip_bf16.h>
#include <math.h>

// Problem constants (fixed by the reference: B=4,S=2048,H=1024,D=4096)
#define H_DIM 1024
#define NBASIS 8
#define K_DIM 9216                // 8*H (spline, k=h*8+j) + H (silu, k=8192+h)
#define K_SILU 8192
#define BM 256                    // block tile (M and O)
#define BK 64                     // K tile (bf16 elements)
#define NKT (K_DIM / BK)          // 144 (even)

typedef __bf16 bf16x8 __attribute__((ext_vector_type(8)));
typedef float f32x4 __attribute__((ext_vector_type(4)));
typedef unsigned short u16x8 __attribute__((ext_vector_type(8)));

__device__ __forceinline__ unsigned short f2bf(float f) {
    __hip_bfloat16 h = __float2bfloat16(f);   // RNE
    return __builtin_bit_cast(unsigned short, h);
}

// ---------------------------------------------------------------------------
// Kernel 1: A[n][h*8+j] = bf16 bases, A[n][8192+h] = bf16 silu(x)
// ---------------------------------------------------------------------------
__global__ void prep_a_kernel(const float* __restrict__ x,
                              unsigned short* __restrict__ A, int total) {
    int idx = blockIdx.x * 256 + threadIdx.x;   // idx = n*H + h
    if (idx >= total) return;
    int n = idx >> 10;
    int h = idx & (H_DIM - 1);
    float v = x[idx];

    float sil = v / (1.0f + __expf(-v));

    float b[11];
#pragma unroll
    for (int i = 0; i < 11; ++i) {
        const float gi  = (float)(i - 3) * 0.4f + (-1.0f);
        const float gi1 = (float)(i - 2) * 0.4f + (-1.0f);
        b[i] = (v >= gi && v < gi1) ? 1.0f : 0.0f;
    }
#pragma unroll
    for (int k = 1; k <= 3; ++k) {
#pragma unroll
        for (int i = 0; i + k < 11; ++i) {
            const float gi   = (float)(i - 3) * 0.4f + (-1.0f);
            const float gi1  = (float)(i - 2) * 0.4f + (-1.0f);
            const float gik  = (float)(i + k - 3) * 0.4f + (-1.0f);
            const float gik1 = (float)(i + k - 2) * 0.4f + (-1.0f);
            float left  = (v - gi)   * (1.0f / (gik - gi));
            float right = (gik1 - v) * (1.0f / (gik1 - gi1));
            b[i] = left * b[i] + right * b[i + 1];
        }
    }

    u16x8 pack;
#pragma unroll
    for (int j = 0; j < NBASIS; ++j) pack[j] = f2bf(b[j]);

    size_t rowBase = (size_t)n * K_DIM;
    *reinterpret_cast<u16x8*>(A + rowBase + (size_t)h * 8) = pack;
    A[rowBase + K_SILU + h] = f2bf(sil);
}

// ---------------------------------------------------------------------------
// Kernel 2: B[o][h*8+j] = bf16(sw*scaler), B[o][8192+h] = bf16(bw)
// ---------------------------------------------------------------------------
__global__ void prep_b_kernel(const float* __restrict__ bw,
                              const float* __restrict__ sw,
                              const float* __restrict__ ss,
                              unsigned short* __restrict__ Bm, int total) {
    int idx = blockIdx.x * 256 + threadIdx.x;   // idx = o*H + h
    if (idx >= total) return;

    const float4* p = (const float4*)(sw + (size_t)idx * 8);
    float4 w0 = p[0], w1 = p[1];
    float sc = ss[idx];

    u16x8 pack;
    pack[0] = f2bf(w0.x * sc); pack[1] = f2bf(w0.y * sc);
    pack[2] = f2bf(w0.z * sc); pack[3] = f2bf(w0.w * sc);
    pack[4] = f2bf(w1.x * sc); pack[5] = f2bf(w1.y * sc);
    pack[6] = f2bf(w1.z * sc); pack[7] = f2bf(w1.w * sc);

    int o = idx >> 10;
    int h = idx & (H_DIM - 1);
    size_t rowBase = (size_t)o * K_DIM;
    *reinterpret_cast<u16x8*>(Bm + rowBase + (size_t)h * 8) = pack;
    Bm[rowBase + K_SILU + h] = f2bf(bw[idx]);
}

// ---------------------------------------------------------------------------
// Kernel 3: C = gelu(A @ B^T) — 256x256 tile, 8-wave, 8-phase counted-vmcnt
// (T3+T4), chunk-XOR conflict-free LDS (T2, measured 0 conflicts in r1),
// setprio (T5), bijective XCD swizzle (T1).
// Round-3 changes vs the 520us r1 kernel:
//   * 16x16x32 MFMA restored (32x32's hi-dependent k-chunk conflicts with
//     the staging swizzle: measured 6.6e7 bank conflicts, ~4 cyc/read).
//   * resident bF0/bF1 register banks: ph4/ph8 re-read of the B0 half
//     eliminated (28 -> 24 ds_read_b128 per K-tile per wave).
//   * schedule un-pinned: no sched_barrier(0), no forced lgkmcnt(0) drains.
//     All LDS reads are compiler-generated, so operand waits are counted
//     lgkmcnt(N) inserted by the compiler (rule #18 applies to asm reads
//     only). Raw s_barrier is boxed by ""::"memory" fences so no LDS/VMEM
//     op crosses a barrier; counted vmcnt(6) waits keep their clobbers so
//     VMEM issue order (and the counts) are preserved.
// ---------------------------------------------------------------------------
#define FENCE()      asm volatile("" ::: "memory")
#define BARRIER()    do { FENCE(); __builtin_amdgcn_s_barrier(); FENCE(); } while (0)
#define WAIT_VM6()   asm volatile("s_waitcnt vmcnt(6)" ::: "memory")
#define HINT_LGKM8() asm volatile("s_waitcnt lgkmcnt(8)" ::: "memory")

// Load NF*2 fragments (NF row-blocks x kk=0,1) from one LDS half-tile.
// Chunk-XOR swizzle: logical chunk c at row r lives in slot c ^ (r&7).
template<int NF>
__device__ __forceinline__ void load_frags(const unsigned short* hp, int rbase,
                                           int l16, int quad, bf16x8* f) {
#pragma unroll
    for (int i = 0; i < NF; ++i)
#pragma unroll
        for (int kk = 0; kk < 2; ++kk)
            f[i * 2 + kk] = *reinterpret_cast<const bf16x8*>(
                &hp[(rbase + i * 16 + l16) * 64 +
                    ((((kk << 2) + quad) ^ (l16 & 7)) << 3)]);
}

template<int QA, int QB>
__device__ __forceinline__ void mfma_quad(const bf16x8* aF, const bf16x8* bF,
                                          f32x4 (&acc)[8][4]) {
    __builtin_amdgcn_s_setprio(1);
#pragma unroll
    for (int m2 = 0; m2 < 4; ++m2)
#pragma unroll
        for (int n2 = 0; n2 < 2; ++n2)
#pragma unroll
            for (int kk = 0; kk < 2; ++kk)
                acc[QA * 4 + m2][QB * 2 + n2] =
                    __builtin_amdgcn_mfma_f32_16x16x32_bf16(
                        aF[m2 * 2 + kk], bF[n2 * 2 + kk],
                        acc[QA * 4 + m2][QB * 2 + n2], 0, 0, 0);
    __builtin_amdgcn_s_setprio(0);
}

__global__ __launch_bounds__(512, 2) void gemm_kan(
    const unsigned short* __restrict__ A,
    const unsigned short* __restrict__ B,
    float* __restrict__ out, int M, int D) {

    // 2 dbuf x {A0,A1,B0,B1} halves of 128x64 bf16 = 128 KiB
    __shared__ __align__(16) unsigned short lds[2][4][128 * 64];

    const int tid  = threadIdx.x;
    const int lane = tid & 63;
    const int w    = tid >> 6;          // wave 0..7
    const int wr   = w >> 2;            // 0..1  (M half)
    const int wc   = w & 3;             // 0..3  (N quarter)
    const int quad = lane >> 4, l16 = lane & 15;

    // T1: bijective XCD swizzle (nwg = 512, 512 % 8 == 0)
    const int nwg = gridDim.x;
    const int cpx = nwg >> 3;
    int bid = blockIdx.x;
    bid = (bid & 7) * cpx + (bid >> 3);
    const int nOB  = D / BM;            // 16
    const int mBlk = bid / nOB;
    const int oBlk = bid % nOB;

    // ---- staging geometry (verified r1: 0 bank conflicts) -----------------
    // Half-tile = 128 rows x 64 bf16 (16 KiB); wave w stages rows
    // [w*16, w*16+16) as 2 x global_load_lds (1024 B each, linear dest).
    // Source pre-swizzled: global chunk (lane&7)^(lane>>3) -> slot lane&7.
    // A-half q = rows {wr*128 + q*64 + [0,64)}; B-half q = {wc*64 + q*32 + [0,32)}.
    const int sub = lane >> 3;
    const int cg  = ((lane & 7) ^ sub) * 8;
    const unsigned short *sA[2][2], *sB[2][2];
#pragma unroll
    for (int h = 0; h < 2; ++h)
#pragma unroll
        for (int l = 0; l < 2; ++l) {
            const int r  = w * 16 + l * 8 + sub;          // 0..127
            const int gA = mBlk * BM + (r >> 6) * 128 + h * 64 + (r & 63);
            const int gB = oBlk * BM + (r >> 5) * 64  + h * 32 + (r & 31);
            sA[h][l] = A + (size_t)gA * K_DIM + cg;
            sB[h][l] = B + (size_t)gB * K_DIM + cg;
        }
    const int ldsOff = w * 1024;        // elements; +l*512 per load

    auto stageA = [&](int db, int h, int kt) {
#pragma unroll
        for (int l = 0; l < 2; ++l)
            __builtin_amdgcn_global_load_lds(
                (const __attribute__((address_space(1))) void*)(sA[h][l] + (size_t)kt * BK),
                (__attribute__((address_space(3))) void*)(&lds[db][h][ldsOff + l * 512]),
                16, 0, 0);
    };
    auto stageB = [&](int db, int h, int kt) {
#pragma unroll
        for (int l = 0; l < 2; ++l)
            __builtin_amdgcn_global_load_lds(
                (const __attribute__((address_space(1))) void*)(sB[h][l] + (size_t)kt * BK),
                (__attribute__((address_space(3))) void*)(&lds[db][2 + h][ldsOff + l * 512]),
                16, 0, 0);
    };

    f32x4 acc[8][4];
#pragma unroll
    for (int i = 0; i < 8; ++i)
#pragma unroll
        for (int j = 0; j < 4; ++j)
            acc[i][j] = (f32x4){0.f, 0.f, 0.f, 0.f};
    bf16x8 aF[8], bF0[4], bF1[4];

    // ---- prologue: tile0 (all 4 halves, buf0) + tile1 {A0,B1,A1} (buf1) ---
    stageA(0, 0, 0); stageB(0, 1, 0); stageA(0, 1, 0); stageB(0, 0, 0);
    stageA(1, 0, 1); stageB(1, 1, 1); stageA(1, 1, 1);
    WAIT_VM6();                          // tile0 complete; 3 halves in flight
    BARRIER();

    // ---- main loop: 2 K-tiles / iteration, 8 phases -----------------------
    // Quadrant order per K-tile: (QA,QB) = (0,0)(0,1)(1,1)(1,0).
    // B0 lives in bF0 (ph1->ph4), B1 in bF1 (ph2->ph3); ph4/ph8 issue no
    // ds_reads. Stage slots/targets identical to r1 (safety audit holds:
    // each staged half's last ds_read is >= 1 phase-barrier-pair earlier;
    // bF0's LDS source is overwritten only after its last register use).
    for (int it = 0; it < NKT / 2; ++it) {
        const int t  = it << 1;                          // buf0 tile
        const int t2 = (t + 2 < NKT) ? t + 2 : NKT - 1;  // clamp keeps vmcnt
        const int t3 = (t + 3 < NKT) ? t + 3 : NKT - 1;  // counts uniform

        // ph1: quad(0,0) of t (buf0); stage B0(t+1)->buf1
        load_frags<4>(&lds[0][0][0], wr * 64, l16, quad, aF);
        load_frags<2>(&lds[0][2][0], wc * 32, l16, quad, bF0);
        stageB(1, 0, t + 1);
        HINT_LGKM8();
        BARRIER();
        mfma_quad<0, 0>(aF, bF0, acc);
        BARRIER();

        // ph2: quad(0,1); stage A0(t+2)->buf0 (A0 last read ph1)
        load_frags<2>(&lds[0][3][0], wc * 32, l16, quad, bF1);
        stageA(0, 0, t2);
        BARRIER();
        mfma_quad<0, 1>(aF, bF1, acc);
        BARRIER();

        // ph3: quad(1,1); stage B1(t+2)->buf0 (B1 last read ph2)
        load_frags<4>(&lds[0][1][0], wr * 64, l16, quad, aF);
        stageB(0, 1, t2);
        BARRIER();
        mfma_quad<1, 1>(aF, bF1, acc);
        BARRIER();

        // ph4: quad(1,0) — no ds_reads (bF0 resident); stage A1(t+2)->buf0
        stageA(0, 1, t2);
        BARRIER();
        mfma_quad<1, 0>(aF, bF0, acc);
        WAIT_VM6();                      // tile t+1 fully staged
        BARRIER();

        // ph5: quad(0,0) of t+1 (buf1); stage B0(t+2)->buf0 (buf0 reads done)
        load_frags<4>(&lds[1][0][0], wr * 64, l16, quad, aF);
        load_frags<2>(&lds[1][2][0], wc * 32, l16, quad, bF0);
        stageB(0, 0, t2);
        HINT_LGKM8();
        BARRIER();
        mfma_quad<0, 0>(aF, bF0, acc);
        BARRIER();

        // ph6: quad(0,1); stage A0(t+3)->buf1
        load_frags<2>(&lds[1][3][0], wc * 32, l16, quad, bF1);
        stageA(1, 0, t3);
        BARRIER();
        mfma_quad<0, 1>(aF, bF1, acc);
        BARRIER();

        // ph7: quad(1,1); stage B1(t+3)->buf1
        load_frags<4>(&lds[1][1][0], wr * 64, l16, quad, aF);
        stageB(1, 1, t3);
        BARRIER();
        mfma_quad<1, 1>(aF, bF1, acc);
        BARRIER();

        // ph8: quad(1,0) — no ds_reads (bF0 resident); stage A1(t+3)->buf1
        stageA(1, 1, t3);
        BARRIER();
        mfma_quad<1, 0>(aF, bF0, acc);
        WAIT_VM6();                      // tile t+2 fully staged
        BARRIER();
    }
    asm volatile("s_waitcnt vmcnt(0)" ::: "memory");  // drain tail prefetch

    // ---- epilogue: exact (erf) GELU, fp32 store ---------------------------
    const int mBase = mBlk * BM + wr * 128;
    const int oBase = oBlk * BM + wc * 64 + l16;
#pragma unroll
    for (int mi = 0; mi < 8; ++mi) {
#pragma unroll
        for (int ni = 0; ni < 4; ++ni) {
            const int o = oBase + ni * 16;
#pragma unroll
            for (int r = 0; r < 4; ++r) {
                const int m = mBase + mi * 16 + quad * 4 + r;
                float v = acc[mi][ni][r];
                float gv = 0.5f * v * (1.0f + erff(v * 0.70710678118654752f));
                out[(size_t)m * D + o] = gv;
            }
        }
    }
}

// ---------------------------------------------------------------------------
extern "C" void kernel_launch(void* const* d_in, const int* in_sizes, int n_in,
                              void* d_out, int out_size, void* d_ws, size_t ws_size,
                              hipStream_t stream) {
    const float* x  = (const float*)d_in[0];   // (B,S,H)
    const float* bw = (const float*)d_in[1];   // (D,H)
    const float* sw = (const float*)d_in[2];   // (D,H,8)
    const float* ss = (const float*)d_in[3];   // (D,H)
    float* out = (float*)d_out;

    const int M = in_sizes[0] / H_DIM;         // 8192
    const int D = in_sizes[1] / H_DIM;         // 4096

    unsigned short* Aws = (unsigned short*)d_ws;              // M x K bf16
    unsigned short* Bws = Aws + (size_t)M * K_DIM;            // D x K bf16

    const int totA = M * H_DIM;
    prep_a_kernel<<<(totA + 255) / 256, 256, 0, stream>>>(x, Aws, totA);
    const int totB = D * H_DIM;
    prep_b_kernel<<<(totB + 255) / 256, 256, 0, stream>>>(bw, sw, ss, Bws, totB);

    dim3 grid((M / BM) * (D / BM));            // 32*16 = 512 blocks
    gemm_kan<<<grid, 512, 0, stream>>>(Aws, Bws, out, M, D);
}

// Round 4
// 738.040 us; speedup vs baseline: 1.1329x; 1.0175x over previous
//
#include <hip/hip_runtime.h>
#include <hip/hip_bf16.h>
#include <math.h>

// Problem constants (fixed by the reference: B=4,S=2048,H=1024,D=4096)
#define H_DIM 1024
#define NBASIS 8
#define K_DIM 9216                // 8*H (spline, k=h*8+j) + H (silu, k=8192+h)
#define K_SILU 8192
#define BM 256                    // block tile (M and O)
#define BK 64                    // K tile (bf16 elements)
#define NKT (K_DIM / BK)          // 144 (even)

typedef __bf16 bf16x8 __attribute__((ext_vector_type(8)));
typedef float f32x4 __attribute__((ext_vector_type(4)));
typedef unsigned short u16x8 __attribute__((ext_vector_type(8)));
typedef unsigned short u16x4 __attribute__((ext_vector_type(4)));
typedef unsigned short u16x2 __attribute__((ext_vector_type(2)));

__device__ __forceinline__ unsigned short f2bf(float f) {
    __hip_bfloat16 h = __float2bfloat16(f);   // RNE
    return __builtin_bit_cast(unsigned short, h);
}

// Cox-de Boor cubic, knots g[i] = (i-3)*0.4f - 1.0f (fp32, exactly as the
// reference; arithmetic and order identical to the verified r0-r3 kernels).
__device__ __forceinline__ void spline_bases(float v, float* __restrict__ b8) {
    float b[11];
#pragma unroll
    for (int i = 0; i < 11; ++i) {
        const float gi  = (float)(i - 3) * 0.4f + (-1.0f);
        const float gi1 = (float)(i - 2) * 0.4f + (-1.0f);
        b[i] = (v >= gi && v < gi1) ? 1.0f : 0.0f;
    }
#pragma unroll
    for (int k = 1; k <= 3; ++k) {
#pragma unroll
        for (int i = 0; i + k < 11; ++i) {
            const float gi   = (float)(i - 3) * 0.4f + (-1.0f);
            const float gi1  = (float)(i - 2) * 0.4f + (-1.0f);
            const float gik  = (float)(i + k - 3) * 0.4f + (-1.0f);
            const float gik1 = (float)(i + k - 2) * 0.4f + (-1.0f);
            float left  = (v - gi)   * (1.0f / (gik - gi));
            float right = (gik1 - v) * (1.0f / (gik1 - gi1));
            b[i] = left * b[i] + right * b[i + 1];
        }
    }
#pragma unroll
    for (int j = 0; j < NBASIS; ++j) b8[j] = b[j];
}

// ---------------------------------------------------------------------------
// Fused prep kernel (round 4): one dispatch covers both workspace builds.
//   A-path blocks (first nABlk): 4 (n,h) pairs / thread.
//     loads : float4 x            (16 B/lane, coalesced)
//     stores: 4 x u16x8 bases     (64 B/lane contiguous) + u16x4 silu (8 B)
//   B-path blocks: 2 (o,h) pairs / thread.
//     loads : 4 x float4 sw (64 B) + float2 ss + float2 bw
//     stores: 2 x u16x8           (32 B/lane) + u16x2 base-weight (4 B)
// Per-element math identical to r0-r3 (absmax-critical).
// ---------------------------------------------------------------------------
__global__ void prep_fused(const float* __restrict__ x,
                           const float* __restrict__ bw,
                           const float* __restrict__ sw,
                           const float* __restrict__ ss,
                           unsigned short* __restrict__ A,
                           unsigned short* __restrict__ Bm,
                           int nABlk) {
    if ((int)blockIdx.x < nABlk) {
        // ---- A path: idx = 4*t .. 4*t+3, all same row n (H % 4 == 0) ------
        const int t   = blockIdx.x * 256 + threadIdx.x;
        const int idx = t * 4;
        const int n   = idx >> 10;
        const int h   = idx & (H_DIM - 1);
        const float4 xv = *reinterpret_cast<const float4*>(x + idx);
        const float vs[4] = {xv.x, xv.y, xv.z, xv.w};

        u16x8 packs[4];
        u16x4 silus;
#pragma unroll
        for (int e = 0; e < 4; ++e) {
            const float v = vs[e];
            float b8[NBASIS];
            spline_bases(v, b8);
#pragma unroll
            for (int j = 0; j < NBASIS; ++j) packs[e][j] = f2bf(b8[j]);
            silus[e] = f2bf(v / (1.0f + __expf(-v)));
        }
        const size_t rowBase = (size_t)n * K_DIM;
        u16x8* dst = reinterpret_cast<u16x8*>(A + rowBase + (size_t)h * 8);
#pragma unroll
        for (int e = 0; e < 4; ++e) dst[e] = packs[e];
        *reinterpret_cast<u16x4*>(A + rowBase + K_SILU + h) = silus;
    } else {
        // ---- B path: idx = 2*t .. 2*t+1, same row o (H % 2 == 0) ----------
        const int t   = (blockIdx.x - nABlk) * 256 + threadIdx.x;
        const int idx = t * 2;
        const int o   = idx >> 10;
        const int h   = idx & (H_DIM - 1);
        const float4* p = reinterpret_cast<const float4*>(sw + (size_t)idx * 8);
        const float2 scv = *reinterpret_cast<const float2*>(ss + idx);
        const float2 bwv = *reinterpret_cast<const float2*>(bw + idx);
        const float sc[2] = {scv.x, scv.y};

        u16x8 packs[2];
#pragma unroll
        for (int e = 0; e < 2; ++e) {
            float4 w0 = p[e * 2], w1 = p[e * 2 + 1];
            packs[e][0] = f2bf(w0.x * sc[e]); packs[e][1] = f2bf(w0.y * sc[e]);
            packs[e][2] = f2bf(w0.z * sc[e]); packs[e][3] = f2bf(w0.w * sc[e]);
            packs[e][4] = f2bf(w1.x * sc[e]); packs[e][5] = f2bf(w1.y * sc[e]);
            packs[e][6] = f2bf(w1.z * sc[e]); packs[e][7] = f2bf(w1.w * sc[e]);
        }
        const size_t rowBase = (size_t)o * K_DIM;
        u16x8* dst = reinterpret_cast<u16x8*>(Bm + rowBase + (size_t)h * 8);
        dst[0] = packs[0];
        dst[1] = packs[1];
        u16x2 bwp; bwp[0] = f2bf(bwv.x); bwp[1] = f2bf(bwv.y);
        *reinterpret_cast<u16x2*>(Bm + rowBase + K_SILU + h) = bwp;
    }
}

// ---------------------------------------------------------------------------
// Kernel 3: C = gelu(A @ B^T) — 256x256 tile, 8-wave, 8-phase counted-vmcnt
// (T3+T4), chunk-XOR conflict-free LDS (T2, measured 0 conflicts), setprio
// (T5), bijective XCD swizzle (T1). UNCHANGED from round 3 (518 us, 0
// conflicts, MfmaUtil 54): this round attacks the prep gap; keeping the GEMM
// byte-identical separates the two effects in the counters.
// ---------------------------------------------------------------------------
#define FENCE()      asm volatile("" ::: "memory")
#define BARRIER()    do { FENCE(); __builtin_amdgcn_s_barrier(); FENCE(); } while (0)
#define WAIT_VM6()   asm volatile("s_waitcnt vmcnt(6)" ::: "memory")
#define HINT_LGKM8() asm volatile("s_waitcnt lgkmcnt(8)" ::: "memory")

// Load NF*2 fragments (NF row-blocks x kk=0,1) from one LDS half-tile.
// Chunk-XOR swizzle: logical chunk c at row r lives in slot c ^ (r&7).
template<int NF>
__device__ __forceinline__ void load_frags(const unsigned short* hp, int rbase,
                                           int l16, int quad, bf16x8* f) {
#pragma unroll
    for (int i = 0; i < NF; ++i)
#pragma unroll
        for (int kk = 0; kk < 2; ++kk)
            f[i * 2 + kk] = *reinterpret_cast<const bf16x8*>(
                &hp[(rbase + i * 16 + l16) * 64 +
                    ((((kk << 2) + quad) ^ (l16 & 7)) << 3)]);
}

template<int QA, int QB>
__device__ __forceinline__ void mfma_quad(const bf16x8* aF, const bf16x8* bF,
                                          f32x4 (&acc)[8][4]) {
    __builtin_amdgcn_s_setprio(1);
#pragma unroll
    for (int m2 = 0; m2 < 4; ++m2)
#pragma unroll
        for (int n2 = 0; n2 < 2; ++n2)
#pragma unroll
            for (int kk = 0; kk < 2; ++kk)
                acc[QA * 4 + m2][QB * 2 + n2] =
                    __builtin_amdgcn_mfma_f32_16x16x32_bf16(
                        aF[m2 * 2 + kk], bF[n2 * 2 + kk],
                        acc[QA * 4 + m2][QB * 2 + n2], 0, 0, 0);
    __builtin_amdgcn_s_setprio(0);
}

__global__ __launch_bounds__(512, 2) void gemm_kan(
    const unsigned short* __restrict__ A,
    const unsigned short* __restrict__ B,
    float* __restrict__ out, int M, int D) {

    // 2 dbuf x {A0,A1,B0,B1} halves of 128x64 bf16 = 128 KiB
    __shared__ __align__(16) unsigned short lds[2][4][128 * 64];

    const int tid  = threadIdx.x;
    const int lane = tid & 63;
    const int w    = tid >> 6;          // wave 0..7
    const int wr   = w >> 2;            // 0..1  (M half)
    const int wc   = w & 3;             // 0..3  (N quarter)
    const int quad = lane >> 4, l16 = lane & 15;

    // T1: bijective XCD swizzle (nwg = 512, 512 % 8 == 0)
    const int nwg = gridDim.x;
    const int cpx = nwg >> 3;
    int bid = blockIdx.x;
    bid = (bid & 7) * cpx + (bid >> 3);
    const int nOB  = D / BM;            // 16
    const int mBlk = bid / nOB;
    const int oBlk = bid % nOB;

    // ---- staging geometry (verified: 0 bank conflicts) --------------------
    // Half-tile = 128 rows x 64 bf16 (16 KiB); wave w stages rows
    // [w*16, w*16+16) as 2 x global_load_lds (1024 B each, linear dest).
    // Source pre-swizzled: global chunk (lane&7)^(lane>>3) -> slot lane&7.
    // A-half q = rows {wr*128 + q*64 + [0,64)}; B-half q = {wc*64 + q*32 + [0,32)}.
    const int sub = lane >> 3;
    const int cg  = ((lane & 7) ^ sub) * 8;
    const unsigned short *sA[2][2], *sB[2][2];
#pragma unroll
    for (int h = 0; h < 2; ++h)
#pragma unroll
        for (int l = 0; l < 2; ++l) {
            const int r  = w * 16 + l * 8 + sub;          // 0..127
            const int gA = mBlk * BM + (r >> 6) * 128 + h * 64 + (r & 63);
            const int gB = oBlk * BM + (r >> 5) * 64  + h * 32 + (r & 31);
            sA[h][l] = A + (size_t)gA * K_DIM + cg;
            sB[h][l] = B + (size_t)gB * K_DIM + cg;
        }
    const int ldsOff = w * 1024;        // elements; +l*512 per load

    auto stageA = [&](int db, int h, int kt) {
#pragma unroll
        for (int l = 0; l < 2; ++l)
            __builtin_amdgcn_global_load_lds(
                (const __attribute__((address_space(1))) void*)(sA[h][l] + (size_t)kt * BK),
                (__attribute__((address_space(3))) void*)(&lds[db][h][ldsOff + l * 512]),
                16, 0, 0);
    };
    auto stageB = [&](int db, int h, int kt) {
#pragma unroll
        for (int l = 0; l < 2; ++l)
            __builtin_amdgcn_global_load_lds(
                (const __attribute__((address_space(1))) void*)(sB[h][l] + (size_t)kt * BK),
                (__attribute__((address_space(3))) void*)(&lds[db][2 + h][ldsOff + l * 512]),
                16, 0, 0);
    };

    f32x4 acc[8][4];
#pragma unroll
    for (int i = 0; i < 8; ++i)
#pragma unroll
        for (int j = 0; j < 4; ++j)
            acc[i][j] = (f32x4){0.f, 0.f, 0.f, 0.f};
    bf16x8 aF[8], bF0[4], bF1[4];

    // ---- prologue: tile0 (all 4 halves, buf0) + tile1 {A0,B1,A1} (buf1) ---
    stageA(0, 0, 0); stageB(0, 1, 0); stageA(0, 1, 0); stageB(0, 0, 0);
    stageA(1, 0, 1); stageB(1, 1, 1); stageA(1, 1, 1);
    WAIT_VM6();                          // tile0 complete; 3 halves in flight
    BARRIER();

    // ---- main loop: 2 K-tiles / iteration, 8 phases -----------------------
    // Quadrant order per K-tile: (QA,QB) = (0,0)(0,1)(1,1)(1,0).
    // B0 lives in bF0 (ph1->ph4), B1 in bF1 (ph2->ph3); ph4/ph8 issue no
    // ds_reads. Stage slot/target audit: each staged half's last ds_read is
    // >= 1 phase-barrier-pair earlier; bF0's LDS source is overwritten only
    // after its last register use.
    for (int it = 0; it < NKT / 2; ++it) {
        const int t  = it << 1;                          // buf0 tile
        const int t2 = (t + 2 < NKT) ? t + 2 : NKT - 1;  // clamp keeps vmcnt
        const int t3 = (t + 3 < NKT) ? t + 3 : NKT - 1;  // counts uniform

        // ph1: quad(0,0) of t (buf0); stage B0(t+1)->buf1
        load_frags<4>(&lds[0][0][0], wr * 64, l16, quad, aF);
        load_frags<2>(&lds[0][2][0], wc * 32, l16, quad, bF0);
        stageB(1, 0, t + 1);
        HINT_LGKM8();
        BARRIER();
        mfma_quad<0, 0>(aF, bF0, acc);
        BARRIER();

        // ph2: quad(0,1); stage A0(t+2)->buf0 (A0 last read ph1)
        load_frags<2>(&lds[0][3][0], wc * 32, l16, quad, bF1);
        stageA(0, 0, t2);
        BARRIER();
        mfma_quad<0, 1>(aF, bF1, acc);
        BARRIER();

        // ph3: quad(1,1); stage B1(t+2)->buf0 (B1 last read ph2)
        load_frags<4>(&lds[0][1][0], wr * 64, l16, quad, aF);
        stageB(0, 1, t2);
        BARRIER();
        mfma_quad<1, 1>(aF, bF1, acc);
        BARRIER();

        // ph4: quad(1,0) — no ds_reads (bF0 resident); stage A1(t+2)->buf0
        stageA(0, 1, t2);
        BARRIER();
        mfma_quad<1, 0>(aF, bF0, acc);
        WAIT_VM6();                      // tile t+1 fully staged
        BARRIER();

        // ph5: quad(0,0) of t+1 (buf1); stage B0(t+2)->buf0 (buf0 reads done)
        load_frags<4>(&lds[1][0][0], wr * 64, l16, quad, aF);
        load_frags<2>(&lds[1][2][0], wc * 32, l16, quad, bF0);
        stageB(0, 0, t2);
        HINT_LGKM8();
        BARRIER();
        mfma_quad<0, 0>(aF, bF0, acc);
        BARRIER();

        // ph6: quad(0,1); stage A0(t+3)->buf1
        load_frags<2>(&lds[1][3][0], wc * 32, l16, quad, bF1);
        stageA(1, 0, t3);
        BARRIER();
        mfma_quad<0, 1>(aF, bF1, acc);
        BARRIER();

        // ph7: quad(1,1); stage B1(t+3)->buf1
        load_frags<4>(&lds[1][1][0], wr * 64, l16, quad, aF);
        stageB(1, 1, t3);
        BARRIER();
        mfma_quad<1, 1>(aF, bF1, acc);
        BARRIER();

        // ph8: quad(1,0) — no ds_reads (bF0 resident); stage A1(t+3)->buf1
        stageA(1, 1, t3);
        BARRIER();
        mfma_quad<1, 0>(aF, bF0, acc);
        WAIT_VM6();                      // tile t+2 fully staged
        BARRIER();
    }
    asm volatile("s_waitcnt vmcnt(0)" ::: "memory");  // drain tail prefetch

    // ---- epilogue: exact (erf) GELU, fp32 store ---------------------------
    const int mBase = mBlk * BM + wr * 128;
    const int oBase = oBlk * BM + wc * 64 + l16;
#pragma unroll
    for (int mi = 0; mi < 8; ++mi) {
#pragma unroll
        for (int ni = 0; ni < 4; ++ni) {
            const int o = oBase + ni * 16;
#pragma unroll
            for (int r = 0; r < 4; ++r) {
                const int m = mBase + mi * 16 + quad * 4 + r;
                float v = acc[mi][ni][r];
                float gv = 0.5f * v * (1.0f + erff(v * 0.70710678118654752f));
                out[(size_t)m * D + o] = gv;
            }
        }
    }
}

// ---------------------------------------------------------------------------
extern "C" void kernel_launch(void* const* d_in, const int* in_sizes, int n_in,
                              void* d_out, int out_size, void* d_ws, size_t ws_size,
                              hipStream_t stream) {
    const float* x  = (const float*)d_in[0];   // (B,S,H)
    const float* bw = (const float*)d_in[1];   // (D,H)
    const float* sw = (const float*)d_in[2];   // (D,H,8)
    const float* ss = (const float*)d_in[3];   // (D,H)
    float* out = (float*)d_out;

    const int M = in_sizes[0] / H_DIM;         // 8192
    const int D = in_sizes[1] / H_DIM;         // 4096

    unsigned short* Aws = (unsigned short*)d_ws;              // M x K bf16
    unsigned short* Bws = Aws + (size_t)M * K_DIM;            // D x K bf16

    const int nABlk = (M * H_DIM / 4) / 256;   // 8192 (exact: M*H % 1024 == 0)
    const int nBBlk = (D * H_DIM / 2) / 256;   // 8192 (exact)
    prep_fused<<<nABlk + nBBlk, 256, 0, stream>>>(x, bw, sw, ss, Aws, Bws, nABlk);

    dim3 grid((M / BM) * (D / BM));            // 32*16 = 512 blocks
    gemm_kan<<<grid, 512, 0, stream>>>(Aws, Bws, out, M, D);
}

// Round 5
// 729.385 us; speedup vs baseline: 1.1463x; 1.0119x over previous
//
#include <hip/hip_runtime.h>
#include <hip/hip_bf16.h>
#include <math.h>

// Problem constants (fixed by the reference: B=4,S=2048,H=1024,D=4096)
#define H_DIM 1024
#define NBASIS 8
#define K_DIM 9216                // 8*H (spline, k=h*8+j) + H (silu, k=8192+h)
#define K_SILU 8192
#define BM 256                    // block tile (M and O)
#define BK 64                     // K tile (bf16 elements)
#define NKT (K_DIM / BK)          // 144 (even)

typedef __bf16 bf16x8 __attribute__((ext_vector_type(8)));
typedef float f32x4 __attribute__((ext_vector_type(4)));
typedef unsigned short u16x8 __attribute__((ext_vector_type(8)));
typedef unsigned short u16x4 __attribute__((ext_vector_type(4)));
typedef unsigned short u16x2 __attribute__((ext_vector_type(2)));

__device__ __forceinline__ unsigned short f2bf(float f) {
    __hip_bfloat16 h = __float2bfloat16(f);   // RNE
    return __builtin_bit_cast(unsigned short, h);
}

// Cox-de Boor cubic, knots g[i] = (i-3)*0.4f - 1.0f (fp32, exactly as the
// reference; arithmetic and order identical to the verified r0-r4 kernels).
__device__ __forceinline__ void spline_bases(float v, float* __restrict__ b8) {
    float b[11];
#pragma unroll
    for (int i = 0; i < 11; ++i) {
        const float gi  = (float)(i - 3) * 0.4f + (-1.0f);
        const float gi1 = (float)(i - 2) * 0.4f + (-1.0f);
        b[i] = (v >= gi && v < gi1) ? 1.0f : 0.0f;
    }
#pragma unroll
    for (int k = 1; k <= 3; ++k) {
#pragma unroll
        for (int i = 0; i + k < 11; ++i) {
            const float gi   = (float)(i - 3) * 0.4f + (-1.0f);
            const float gi1  = (float)(i - 2) * 0.4f + (-1.0f);
            const float gik  = (float)(i + k - 3) * 0.4f + (-1.0f);
            const float gik1 = (float)(i + k - 2) * 0.4f + (-1.0f);
            float left  = (v - gi)   * (1.0f / (gik - gi));
            float right = (gik1 - v) * (1.0f / (gik1 - gi1));
            b[i] = left * b[i] + right * b[i + 1];
        }
    }
#pragma unroll
    for (int j = 0; j < NBASIS; ++j) b8[j] = b[j];
}

// ---------------------------------------------------------------------------
// Fused prep kernel (unchanged from round 4; the remaining gap is prep's
// compulsory ~430 MB + fixed overhead — access-pattern changes proved neutral)
// ---------------------------------------------------------------------------
__global__ void prep_fused(const float* __restrict__ x,
                           const float* __restrict__ bw,
                           const float* __restrict__ sw,
                           const float* __restrict__ ss,
                           unsigned short* __restrict__ A,
                           unsigned short* __restrict__ Bm,
                           int nABlk) {
    if ((int)blockIdx.x < nABlk) {
        // ---- A path: idx = 4*t .. 4*t+3, all same row n (H % 4 == 0) ------
        const int t   = blockIdx.x * 256 + threadIdx.x;
        const int idx = t * 4;
        const int n   = idx >> 10;
        const int h   = idx & (H_DIM - 1);
        const float4 xv = *reinterpret_cast<const float4*>(x + idx);
        const float vs[4] = {xv.x, xv.y, xv.z, xv.w};

        u16x8 packs[4];
        u16x4 silus;
#pragma unroll
        for (int e = 0; e < 4; ++e) {
            const float v = vs[e];
            float b8[NBASIS];
            spline_bases(v, b8);
#pragma unroll
            for (int j = 0; j < NBASIS; ++j) packs[e][j] = f2bf(b8[j]);
            silus[e] = f2bf(v / (1.0f + __expf(-v)));
        }
        const size_t rowBase = (size_t)n * K_DIM;
        u16x8* dst = reinterpret_cast<u16x8*>(A + rowBase + (size_t)h * 8);
#pragma unroll
        for (int e = 0; e < 4; ++e) dst[e] = packs[e];
        *reinterpret_cast<u16x4*>(A + rowBase + K_SILU + h) = silus;
    } else {
        // ---- B path: idx = 2*t .. 2*t+1, same row o (H % 2 == 0) ----------
        const int t   = (blockIdx.x - nABlk) * 256 + threadIdx.x;
        const int idx = t * 2;
        const int o   = idx >> 10;
        const int h   = idx & (H_DIM - 1);
        const float4* p = reinterpret_cast<const float4*>(sw + (size_t)idx * 8);
        const float2 scv = *reinterpret_cast<const float2*>(ss + idx);
        const float2 bwv = *reinterpret_cast<const float2*>(bw + idx);
        const float sc[2] = {scv.x, scv.y};

        u16x8 packs[2];
#pragma unroll
        for (int e = 0; e < 2; ++e) {
            float4 w0 = p[e * 2], w1 = p[e * 2 + 1];
            packs[e][0] = f2bf(w0.x * sc[e]); packs[e][1] = f2bf(w0.y * sc[e]);
            packs[e][2] = f2bf(w0.z * sc[e]); packs[e][3] = f2bf(w0.w * sc[e]);
            packs[e][4] = f2bf(w1.x * sc[e]); packs[e][5] = f2bf(w1.y * sc[e]);
            packs[e][6] = f2bf(w1.z * sc[e]); packs[e][7] = f2bf(w1.w * sc[e]);
        }
        const size_t rowBase = (size_t)o * K_DIM;
        u16x8* dst = reinterpret_cast<u16x8*>(Bm + rowBase + (size_t)h * 8);
        dst[0] = packs[0];
        dst[1] = packs[1];
        u16x2 bwp; bwp[0] = f2bf(bwv.x); bwp[1] = f2bf(bwv.y);
        *reinterpret_cast<u16x2*>(Bm + rowBase + K_SILU + h) = bwp;
    }
}

// ---------------------------------------------------------------------------
// Kernel 3: C = gelu(A @ B^T) — 256x256 tile, 8-wave, counted-vmcnt schedule,
// chunk-XOR conflict-free LDS, setprio, bijective XCD swizzle.
// Round-5 changes vs r3/r4 (515 us, MfmaUtil 54):
//   * ONE barrier per phase (was 2). Safety: every staged region's last
//     ds_read is consumed by an MFMA before that wave's end-of-phase barrier
//     (compiler operand waits), so post-barrier the region is quiescent.
//     Same-phase stage targets are disjoint from same-phase read regions
//     (audited ph1-ph8). vmcnt(6) steady-state re-derived: unchanged (tile
//     t+1 complete at ph4's wait, t+2 at ph8's). Reads of a freshly staged
//     buffer remain guarded by WAIT_VM6 + BARRIER at ph4/ph8.
//   * kk hoisted to outer loop in mfma_quad: no back-to-back dependent
//     MFMA pairs (reuse distance 8). Per-acc accumulation order unchanged
//     (kk=0 then kk=1) -> bit-identical.
//   * FENCE after each stage keeps gloads issued before the MFMA cluster
//     (latency hiding); barriers keep fences so no memory op crosses.
// ---------------------------------------------------------------------------
#define FENCE()      asm volatile("" ::: "memory")
#define BARRIER()    do { FENCE(); __builtin_amdgcn_s_barrier(); FENCE(); } while (0)
#define WAIT_VM6()   asm volatile("s_waitcnt vmcnt(6)" ::: "memory")

// Load NF*2 fragments (NF row-blocks x kk=0,1) from one LDS half-tile.
// Chunk-XOR swizzle: logical chunk c at row r lives in slot c ^ (r&7).
template<int NF>
__device__ __forceinline__ void load_frags(const unsigned short* hp, int rbase,
                                           int l16, int quad, bf16x8* f) {
#pragma unroll
    for (int i = 0; i < NF; ++i)
#pragma unroll
        for (int kk = 0; kk < 2; ++kk)
            f[i * 2 + kk] = *reinterpret_cast<const bf16x8*>(
                &hp[(rbase + i * 16 + l16) * 64 +
                    ((((kk << 2) + quad) ^ (l16 & 7)) << 3)]);
}

template<int QA, int QB>
__device__ __forceinline__ void mfma_quad(const bf16x8* aF, const bf16x8* bF,
                                          f32x4 (&acc)[8][4]) {
    __builtin_amdgcn_s_setprio(1);
#pragma unroll
    for (int kk = 0; kk < 2; ++kk)          // kk OUTER: no dependent pairs
#pragma unroll
        for (int m2 = 0; m2 < 4; ++m2)
#pragma unroll
            for (int n2 = 0; n2 < 2; ++n2)
                acc[QA * 4 + m2][QB * 2 + n2] =
                    __builtin_amdgcn_mfma_f32_16x16x32_bf16(
                        aF[m2 * 2 + kk], bF[n2 * 2 + kk],
                        acc[QA * 4 + m2][QB * 2 + n2], 0, 0, 0);
    __builtin_amdgcn_s_setprio(0);
}

__global__ __launch_bounds__(512, 2) void gemm_kan(
    const unsigned short* __restrict__ A,
    const unsigned short* __restrict__ B,
    float* __restrict__ out, int M, int D) {

    // 2 dbuf x {A0,A1,B0,B1} halves of 128x64 bf16 = 128 KiB
    __shared__ __align__(16) unsigned short lds[2][4][128 * 64];

    const int tid  = threadIdx.x;
    const int lane = tid & 63;
    const int w    = tid >> 6;          // wave 0..7
    const int wr   = w >> 2;            // 0..1  (M half)
    const int wc   = w & 3;             // 0..3  (N quarter)
    const int quad = lane >> 4, l16 = lane & 15;

    // T1: bijective XCD swizzle (nwg = 512, 512 % 8 == 0)
    const int nwg = gridDim.x;
    const int cpx = nwg >> 3;
    int bid = blockIdx.x;
    bid = (bid & 7) * cpx + (bid >> 3);
    const int nOB  = D / BM;            // 16
    const int mBlk = bid / nOB;
    const int oBlk = bid % nOB;

    // ---- staging geometry (verified: 0 bank conflicts) --------------------
    // Half-tile = 128 rows x 64 bf16 (16 KiB); wave w stages rows
    // [w*16, w*16+16) as 2 x global_load_lds (1024 B each, linear dest).
    // Source pre-swizzled: global chunk (lane&7)^(lane>>3) -> slot lane&7.
    // A-half q = rows {wr*128 + q*64 + [0,64)}; B-half q = {wc*64 + q*32 + [0,32)}.
    const int sub = lane >> 3;
    const int cg  = ((lane & 7) ^ sub) * 8;
    const unsigned short *sA[2][2], *sB[2][2];
#pragma unroll
    for (int h = 0; h < 2; ++h)
#pragma unroll
        for (int l = 0; l < 2; ++l) {
            const int r  = w * 16 + l * 8 + sub;          // 0..127
            const int gA = mBlk * BM + (r >> 6) * 128 + h * 64 + (r & 63);
            const int gB = oBlk * BM + (r >> 5) * 64  + h * 32 + (r & 31);
            sA[h][l] = A + (size_t)gA * K_DIM + cg;
            sB[h][l] = B + (size_t)gB * K_DIM + cg;
        }
    const int ldsOff = w * 1024;        // elements; +l*512 per load

    auto stageA = [&](int db, int h, int kt) {
#pragma unroll
        for (int l = 0; l < 2; ++l)
            __builtin_amdgcn_global_load_lds(
                (const __attribute__((address_space(1))) void*)(sA[h][l] + (size_t)kt * BK),
                (__attribute__((address_space(3))) void*)(&lds[db][h][ldsOff + l * 512]),
                16, 0, 0);
    };
    auto stageB = [&](int db, int h, int kt) {
#pragma unroll
        for (int l = 0; l < 2; ++l)
            __builtin_amdgcn_global_load_lds(
                (const __attribute__((address_space(1))) void*)(sB[h][l] + (size_t)kt * BK),
                (__attribute__((address_space(3))) void*)(&lds[db][2 + h][ldsOff + l * 512]),
                16, 0, 0);
    };

    f32x4 acc[8][4];
#pragma unroll
    for (int i = 0; i < 8; ++i)
#pragma unroll
        for (int j = 0; j < 4; ++j)
            acc[i][j] = (f32x4){0.f, 0.f, 0.f, 0.f};
    bf16x8 aF[8], bF0[4], bF1[4];

    // ---- prologue: tile0 (all 4 halves, buf0) + tile1 {A0,B1,A1} (buf1) ---
    stageA(0, 0, 0); stageB(0, 1, 0); stageA(0, 1, 0); stageB(0, 0, 0);
    stageA(1, 0, 1); stageB(1, 1, 1); stageA(1, 1, 1);
    WAIT_VM6();                          // tile0 complete; 3 halves in flight
    BARRIER();

    // ---- main loop: 2 K-tiles / iteration, 8 phases, ONE barrier each -----
    // Per phase: [ds_reads; stage; FENCE; MFMA; (WAIT_VM6 at ph4/ph8); BARRIER]
    // Quadrant order per K-tile: (QA,QB) = (0,0)(0,1)(1,1)(1,0).
    // B0 in bF0 (ph1->ph4), B1 in bF1 (ph2->ph3); ph4/ph8 issue no ds_reads.
    for (int it = 0; it < NKT / 2; ++it) {
        const int t  = it << 1;                          // buf0 tile
        const int t2 = (t + 2 < NKT) ? t + 2 : NKT - 1;  // clamp keeps vmcnt
        const int t3 = (t + 3 < NKT) ? t + 3 : NKT - 1;  // counts uniform

        // ph1: quad(0,0) of t (buf0); stage B0(t+1)->buf1.B0 (last read prev ph5)
        load_frags<4>(&lds[0][0][0], wr * 64, l16, quad, aF);
        load_frags<2>(&lds[0][2][0], wc * 32, l16, quad, bF0);
        stageB(1, 0, t + 1);
        FENCE();
        mfma_quad<0, 0>(aF, bF0, acc);
        BARRIER();

        // ph2: quad(0,1); stage A0(t+2)->buf0.A0 (last read ph1)
        load_frags<2>(&lds[0][3][0], wc * 32, l16, quad, bF1);
        stageA(0, 0, t2);
        FENCE();
        mfma_quad<0, 1>(aF, bF1, acc);
        BARRIER();

        // ph3: quad(1,1); stage B1(t+2)->buf0.B1 (last read ph2)
        load_frags<4>(&lds[0][1][0], wr * 64, l16, quad, aF);
        stageB(0, 1, t2);
        FENCE();
        mfma_quad<1, 1>(aF, bF1, acc);
        BARRIER();

        // ph4: quad(1,0) — no ds_reads; stage A1(t+2)->buf0.A1 (last read ph3)
        stageA(0, 1, t2);
        FENCE();
        mfma_quad<1, 0>(aF, bF0, acc);
        WAIT_VM6();                      // tile t+1 fully staged
        BARRIER();

        // ph5: quad(0,0) of t+1 (buf1); stage B0(t+2)->buf0.B0 (last read ph1)
        load_frags<4>(&lds[1][0][0], wr * 64, l16, quad, aF);
        load_frags<2>(&lds[1][2][0], wc * 32, l16, quad, bF0);
        stageB(0, 0, t2);
        FENCE();
        mfma_quad<0, 0>(aF, bF0, acc);
        BARRIER();

        // ph6: quad(0,1); stage A0(t+3)->buf1.A0 (last read ph5)
        load_frags<2>(&lds[1][3][0], wc * 32, l16, quad, bF1);
        stageA(1, 0, t3);
        FENCE();
        mfma_quad<0, 1>(aF, bF1, acc);
        BARRIER();

        // ph7: quad(1,1); stage B1(t+3)->buf1.B1 (last read ph6)
        load_frags<4>(&lds[1][1][0], wr * 64, l16, quad, aF);
        stageB(1, 1, t3);
        FENCE();
        mfma_quad<1, 1>(aF, bF1, acc);
        BARRIER();

        // ph8: quad(1,0) — no ds_reads; stage A1(t+3)->buf1.A1 (last read ph7)
        stageA(1, 1, t3);
        FENCE();
        mfma_quad<1, 0>(aF, bF0, acc);
        WAIT_VM6();                      // tile t+2 fully staged
        BARRIER();
    }
    asm volatile("s_waitcnt vmcnt(0)" ::: "memory");  // drain tail prefetch

    // ---- epilogue: exact (erf) GELU, fp32 store ---------------------------
    const int mBase = mBlk * BM + wr * 128;
    const int oBase = oBlk * BM + wc * 64 + l16;
#pragma unroll
    for (int mi = 0; mi < 8; ++mi) {
#pragma unroll
        for (int ni = 0; ni < 4; ++ni) {
            const int o = oBase + ni * 16;
#pragma unroll
            for (int r = 0; r < 4; ++r) {
                const int m = mBase + mi * 16 + quad * 4 + r;
                float v = acc[mi][ni][r];
                float gv = 0.5f * v * (1.0f + erff(v * 0.70710678118654752f));
                out[(size_t)m * D + o] = gv;
            }
        }
    }
}

// ---------------------------------------------------------------------------
extern "C" void kernel_launch(void* const* d_in, const int* in_sizes, int n_in,
                              void* d_out, int out_size, void* d_ws, size_t ws_size,
                              hipStream_t stream) {
    const float* x  = (const float*)d_in[0];   // (B,S,H)
    const float* bw = (const float*)d_in[1];   // (D,H)
    const float* sw = (const float*)d_in[2];   // (D,H,8)
    const float* ss = (const float*)d_in[3];   // (D,H)
    float* out = (float*)d_out;

    const int M = in_sizes[0] / H_DIM;         // 8192
    const int D = in_sizes[1] / H_DIM;         // 4096

    unsigned short* Aws = (unsigned short*)d_ws;              // M x K bf16
    unsigned short* Bws = Aws + (size_t)M * K_DIM;            // D x K bf16

    const int nABlk = (M * H_DIM / 4) / 256;   // 8192 (exact: M*H % 1024 == 0)
    const int nBBlk = (D * H_DIM / 2) / 256;   // 8192 (exact)
    prep_fused<<<nABlk + nBBlk, 256, 0, stream>>>(x, bw, sw, ss, Aws, Bws, nABlk);

    dim3 grid((M / BM) * (D / BM));            // 32*16 = 512 blocks
    gemm_kan<<<grid, 512, 0, stream>>>(Aws, Bws, out, M, D);
}